// Round 1
// baseline (148.840 us; speedup 1.0000x reference)
//
#include <hip/hip_runtime.h>

// Per-point expert-indexed MLP: h = LeakyReLU(h @ W[idx] + b[idx]) x3.
// Strategy: counting-sort points by expert (16 buckets, segments padded to
// block size) so every 256-thread block of the main kernel is expert-uniform.
// Weights for the block's expert are staged once into LDS (4.8 KB) and read
// at wave-uniform addresses (broadcast, conflict-free). One point per thread,
// fully unrolled fp32 FMA chain, float4 output stores.

#define L_EXP 16
#define IN0   7
#define C0    16
#define C1    32
#define C2    16
#define NEG   0.2f
#define BLK   256

// ws layout (int32):
//   [0..15]   hist (per-expert counts)
//   [16..32]  offs (17 padded segment offsets, offs[16] = padded total)
//   [48..63]  cursor (scatter cursors)
//   [64.. )   perm  (padded total entries)

__global__ void k_hist(const int* __restrict__ idx, int n, int* __restrict__ ws) {
    __shared__ int bins[L_EXP];
    int t = threadIdx.x;
    if (t < L_EXP) bins[t] = 0;
    __syncthreads();
    for (int i = blockIdx.x * blockDim.x + t; i < n; i += gridDim.x * blockDim.x) {
        atomicAdd(&bins[idx[i] & 15], 1);
    }
    __syncthreads();
    if (t < L_EXP) atomicAdd(&ws[t], bins[t]);
}

__global__ void k_scan(int* __restrict__ ws) {
    if (threadIdx.x == 0) {
        int run = 0;
        for (int e = 0; e < L_EXP; ++e) {
            ws[16 + e] = run;
            int c = ws[e];
            run += ((c + BLK - 1) / BLK) * BLK;  // pad each segment to BLK
        }
        ws[32] = run;
    }
}

__global__ void k_scatter(const int* __restrict__ idx, int n, int* __restrict__ ws) {
    __shared__ int lcount[L_EXP];
    __shared__ int gbase[L_EXP];
    int t = threadIdx.x;
    if (t < L_EXP) lcount[t] = 0;
    __syncthreads();
    int i = blockIdx.x * BLK + t;
    int e = 0, r = 0;
    bool act = (i < n);
    if (act) {
        e = idx[i] & 15;
        r = atomicAdd(&lcount[e], 1);
    }
    __syncthreads();
    if (t < L_EXP) gbase[t] = atomicAdd(&ws[48 + t], lcount[t]);
    __syncthreads();
    if (act) {
        int pos = ws[16 + e] + gbase[e] + r;
        ws[64 + pos] = i;
    }
}

__device__ __forceinline__ float4 f4_fma(float s, float4 w, float4 a) {
    a.x = fmaf(s, w.x, a.x);
    a.y = fmaf(s, w.y, a.y);
    a.z = fmaf(s, w.z, a.z);
    a.w = fmaf(s, w.w, a.w);
    return a;
}

__device__ __forceinline__ float4 f4_leaky(float4 a) {
    a.x = fmaxf(a.x, NEG * a.x);
    a.y = fmaxf(a.y, NEG * a.y);
    a.z = fmaxf(a.z, NEG * a.z);
    a.w = fmaxf(a.w, NEG * a.w);
    return a;
}

__global__ void __launch_bounds__(BLK, 2) k_mlp(
    const float* __restrict__ x, const int* __restrict__ meta,
    const float* __restrict__ W0, const float* __restrict__ b0,
    const float* __restrict__ W1, const float* __restrict__ b1,
    const float* __restrict__ W2, const float* __restrict__ b2,
    float* __restrict__ out) {
    __shared__ __align__(16) float sW0[IN0 * C0];  // 112
    __shared__ __align__(16) float sB0[C0];        // 16
    __shared__ __align__(16) float sW1[C0 * C1];   // 512
    __shared__ __align__(16) float sB1[C1];        // 32
    __shared__ __align__(16) float sW2[C1 * C2];   // 512
    __shared__ __align__(16) float sB2[C2];        // 16

    int start = blockIdx.x * BLK;
    int total = meta[32];
    if (start >= total) return;

    // Segment lengths are multiples of BLK and start is a multiple of BLK,
    // so the whole block lies in exactly one expert's padded segment.
    int e = 0;
    while (start >= meta[16 + e + 1]) ++e;
    e = __builtin_amdgcn_readfirstlane(e);

    int t = threadIdx.x;
    // Stage this expert's weights into LDS (coalesced).
    {
        const float* w0p = W0 + e * (IN0 * C0);
        const float* w1p = W1 + e * (C0 * C1);
        const float* w2p = W2 + e * (C1 * C2);
        if (t < IN0 * C0) sW0[t] = w0p[t];
        if (t >= 128 && t < 128 + C0) sB0[t - 128] = b0[e * C0 + (t - 128)];
        if (t >= 160 && t < 160 + C1) sB1[t - 160] = b1[e * C1 + (t - 160)];
        if (t >= 192 && t < 192 + C2) sB2[t - 192] = b2[e * C2 + (t - 192)];
        for (int k = t; k < C0 * C1; k += BLK) sW1[k] = w1p[k];
        for (int k = t; k < C1 * C2; k += BLK) sW2[k] = w2p[k];
    }
    __syncthreads();

    int seg = meta[16 + e];
    int cnt = meta[e];
    int j = start - seg + t;
    if (j >= cnt) return;

    int p = meta[64 + seg + j];

    const float* xp = x + p * IN0;
    float xv[IN0];
#pragma unroll
    for (int c = 0; c < IN0; ++c) xv[c] = xp[c];

    // Layer 0: 7 -> 16
    float h0[C0];
#pragma unroll
    for (int og = 0; og < C0 / 4; ++og) {
        float4 a = *reinterpret_cast<const float4*>(&sB0[og * 4]);
#pragma unroll
        for (int c = 0; c < IN0; ++c) {
            float4 w = *reinterpret_cast<const float4*>(&sW0[c * C0 + og * 4]);
            a = f4_fma(xv[c], w, a);
        }
        a = f4_leaky(a);
        h0[og * 4 + 0] = a.x; h0[og * 4 + 1] = a.y;
        h0[og * 4 + 2] = a.z; h0[og * 4 + 3] = a.w;
    }

    // Layer 1: 16 -> 32
    float h1[C1];
#pragma unroll
    for (int og = 0; og < C1 / 4; ++og) {
        float4 a = *reinterpret_cast<const float4*>(&sB1[og * 4]);
#pragma unroll
        for (int c = 0; c < C0; ++c) {
            float4 w = *reinterpret_cast<const float4*>(&sW1[c * C1 + og * 4]);
            a = f4_fma(h0[c], w, a);
        }
        a = f4_leaky(a);
        h1[og * 4 + 0] = a.x; h1[og * 4 + 1] = a.y;
        h1[og * 4 + 2] = a.z; h1[og * 4 + 3] = a.w;
    }

    // Layer 2: 32 -> 16, store directly (out rows are 64B-aligned)
    float4* outp = reinterpret_cast<float4*>(out + (size_t)p * C2);
#pragma unroll
    for (int og = 0; og < C2 / 4; ++og) {
        float4 a = *reinterpret_cast<const float4*>(&sB2[og * 4]);
#pragma unroll
        for (int c = 0; c < C1; ++c) {
            float4 w = *reinterpret_cast<const float4*>(&sW2[c * C2 + og * 4]);
            a = f4_fma(h1[c], w, a);
        }
        outp[og] = f4_leaky(a);
    }
}

extern "C" void kernel_launch(void* const* d_in, const int* in_sizes, int n_in,
                              void* d_out, int out_size, void* d_ws, size_t ws_size,
                              hipStream_t stream) {
    const float* x  = (const float*)d_in[0];
    const int*   idx = (const int*)d_in[1];
    const float* W0 = (const float*)d_in[2];
    const float* b0 = (const float*)d_in[3];
    const float* W1 = (const float*)d_in[4];
    const float* b1 = (const float*)d_in[5];
    const float* W2 = (const float*)d_in[6];
    const float* b2 = (const float*)d_in[7];
    float* out = (float*)d_out;

    int n = in_sizes[1];  // idx element count == N
    int* ws = (int*)d_ws;

    // zero hist/offs/cursor region (ws is poisoned 0xAA before every launch)
    hipMemsetAsync(ws, 0, 64 * sizeof(int), stream);

    k_hist<<<256, BLK, 0, stream>>>(idx, n, ws);
    k_scan<<<1, 64, 0, stream>>>(ws);

    int nblk = (n + BLK - 1) / BLK;
    k_scatter<<<nblk, BLK, 0, stream>>>(idx, n, ws);

    // padded total <= n + 16*(BLK-1)
    int mblk = (n + L_EXP * (BLK - 1) + BLK - 1) / BLK;
    k_mlp<<<mblk, BLK, 0, stream>>>(x, ws, W0, b0, W1, b1, W2, b2, out);
}

// Round 2
// 145.523 us; speedup vs baseline: 1.0228x; 1.0228x over previous
//
#include <hip/hip_runtime.h>

// Per-point expert-indexed MLP: h = LeakyReLU(h @ W[idx] + b[idx]) x3.
// Counting-sort points by expert (16 buckets, segments padded to BLK) so each
// 256-thread block of the main kernel is expert-uniform. Weights are then
// WAVE-UNIFORM: e is readfirstlane'd and weight pointers are const __restrict__,
// so the compiler emits s_load (scalar cache) for all 1200 weight/bias floats
// and v_fma_f32 with an SGPR weight operand. Zero LDS in the main kernel ->
// no LDS-pipe bottleneck (previous version spent ~3400 cyc/wave on ds_read).
//
// Pipeline (4 dispatches, no memset): k_hist (per-block partial counts, plain
// stores) -> k_scan (1 block: reduce + padded scan + zero cursors) ->
// k_scatter (block-aggregated atomics) -> k_mlp.

#define L_EXP 16
#define IN0   7
#define C0    16
#define C1    32
#define C2    16
#define NEG   0.2f
#define BLK   256
#define HBLK  64   // histogram blocks

// ws layout (int32):
//   [0..15]    counts per expert (written by k_scan)
//   [16..32]   padded segment offsets (17 entries, offs[16] = padded total)
//   [48..63]   scatter cursors (zeroed by k_scan)
//   [64..1087] partial histograms (HBLK x 16, plain stores from k_hist)
//   [2048.. )  perm (padded total entries)
#define WS_PART 64
#define WS_PERM 2048

__global__ void k_hist(const int* __restrict__ idx, int n, int* __restrict__ ws) {
    __shared__ int bins[L_EXP];
    int t = threadIdx.x;
    if (t < L_EXP) bins[t] = 0;
    __syncthreads();
    for (int i = blockIdx.x * blockDim.x + t; i < n; i += gridDim.x * blockDim.x) {
        atomicAdd(&bins[idx[i] & 15], 1);
    }
    __syncthreads();
    if (t < L_EXP) ws[WS_PART + blockIdx.x * L_EXP + t] = bins[t];
}

__global__ void k_scan(int* __restrict__ ws) {
    int t = threadIdx.x;
    if (t < L_EXP) {
        int s = 0;
        for (int b = 0; b < HBLK; ++b) s += ws[WS_PART + b * L_EXP + t];
        ws[t] = s;       // final count
        ws[48 + t] = 0;  // cursor
    }
    __syncthreads();
    if (t == 0) {
        int run = 0;
        for (int e = 0; e < L_EXP; ++e) {
            ws[16 + e] = run;
            run += ((ws[e] + BLK - 1) / BLK) * BLK;  // pad each segment to BLK
        }
        ws[32] = run;
    }
}

__global__ void k_scatter(const int* __restrict__ idx, int n, int* __restrict__ ws) {
    __shared__ int lcount[L_EXP];
    __shared__ int gbase[L_EXP];
    int t = threadIdx.x;
    if (t < L_EXP) lcount[t] = 0;
    __syncthreads();
    int i = blockIdx.x * BLK + t;
    int e = 0, r = 0;
    bool act = (i < n);
    if (act) {
        e = idx[i] & 15;
        r = atomicAdd(&lcount[e], 1);
    }
    __syncthreads();
    if (t < L_EXP) gbase[t] = atomicAdd(&ws[48 + t], lcount[t]);
    __syncthreads();
    if (act) {
        int pos = ws[16 + e] + gbase[e] + r;
        ws[WS_PERM + pos] = i;
    }
}

__device__ __forceinline__ float leaky(float a) {
    return fmaxf(a, NEG * a);
}

__global__ void __launch_bounds__(BLK, 4) k_mlp(
    const float* __restrict__ x, const int* __restrict__ meta,
    const float* __restrict__ W0, const float* __restrict__ b0,
    const float* __restrict__ W1, const float* __restrict__ b1,
    const float* __restrict__ W2, const float* __restrict__ b2,
    float* __restrict__ out) {
    int start = blockIdx.x * BLK;
    int total = meta[32];
    if (start >= total) return;

    // Whole block lies in one expert's padded segment (segments are BLK-padded).
    int e = 0;
    while (start >= meta[16 + e + 1]) ++e;
    e = __builtin_amdgcn_readfirstlane(e);  // wave-uniform -> scalar weight loads

    int seg = meta[16 + e];
    int cnt = meta[e];
    int t = threadIdx.x;
    int j = start - seg + t;
    if (j >= cnt) return;

    int p = meta[WS_PERM + seg + j];

    // Uniform (scalar) weight pointers for this block's expert.
    const float* __restrict__ w0p = W0 + e * (IN0 * C0);
    const float* __restrict__ b0p = b0 + e * C0;
    const float* __restrict__ w1p = W1 + e * (C0 * C1);
    const float* __restrict__ b1p = b1 + e * C1;
    const float* __restrict__ w2p = W2 + e * (C1 * C2);
    const float* __restrict__ b2p = b2 + e * C2;

    const float* __restrict__ xp = x + p * IN0;
    float xv[IN0];
#pragma unroll
    for (int c = 0; c < IN0; ++c) xv[c] = xp[c];

    // Layer 0: 7 -> 16 (weights row-major [in][out], contiguous rows -> s_load_dwordx16)
    float h0[C0];
#pragma unroll
    for (int o = 0; o < C0; ++o) h0[o] = b0p[o];
#pragma unroll
    for (int c = 0; c < IN0; ++c) {
        float hv = xv[c];
#pragma unroll
        for (int o = 0; o < C0; ++o) h0[o] = fmaf(hv, w0p[c * C0 + o], h0[o]);
    }
#pragma unroll
    for (int o = 0; o < C0; ++o) h0[o] = leaky(h0[o]);

    // Layer 1: 16 -> 32
    float h1[C1];
#pragma unroll
    for (int o = 0; o < C1; ++o) h1[o] = b1p[o];
#pragma unroll
    for (int c = 0; c < C0; ++c) {
        float hv = h0[c];
#pragma unroll
        for (int o = 0; o < C1; ++o) h1[o] = fmaf(hv, w1p[c * C1 + o], h1[o]);
    }
#pragma unroll
    for (int o = 0; o < C1; ++o) h1[o] = leaky(h1[o]);

    // Layer 2: 32 -> 16, store directly (out rows are 64B-aligned)
    float h2[C2];
#pragma unroll
    for (int o = 0; o < C2; ++o) h2[o] = b2p[o];
#pragma unroll
    for (int c = 0; c < C1; ++c) {
        float hv = h1[c];
#pragma unroll
        for (int o = 0; o < C2; ++o) h2[o] = fmaf(hv, w2p[c * C2 + o], h2[o]);
    }
    float4* outp = reinterpret_cast<float4*>(out + (size_t)p * C2);
#pragma unroll
    for (int og = 0; og < C2 / 4; ++og) {
        float4 a;
        a.x = leaky(h2[og * 4 + 0]);
        a.y = leaky(h2[og * 4 + 1]);
        a.z = leaky(h2[og * 4 + 2]);
        a.w = leaky(h2[og * 4 + 3]);
        outp[og] = a;
    }
}

extern "C" void kernel_launch(void* const* d_in, const int* in_sizes, int n_in,
                              void* d_out, int out_size, void* d_ws, size_t ws_size,
                              hipStream_t stream) {
    const float* x  = (const float*)d_in[0];
    const int*  idx = (const int*)d_in[1];
    const float* W0 = (const float*)d_in[2];
    const float* b0 = (const float*)d_in[3];
    const float* W1 = (const float*)d_in[4];
    const float* b1 = (const float*)d_in[5];
    const float* W2 = (const float*)d_in[6];
    const float* b2 = (const float*)d_in[7];
    float* out = (float*)d_out;

    int n = in_sizes[1];  // idx element count == N
    int* ws = (int*)d_ws;

    k_hist<<<HBLK, BLK, 0, stream>>>(idx, n, ws);
    k_scan<<<1, BLK, 0, stream>>>(ws);

    int nblk = (n + BLK - 1) / BLK;
    k_scatter<<<nblk, BLK, 0, stream>>>(idx, n, ws);

    // padded total <= n + 16*(BLK-1)
    int mblk = (n + L_EXP * (BLK - 1) + BLK - 1) / BLK;
    k_mlp<<<mblk, BLK, 0, stream>>>(x, ws, W0, b0, W1, b1, W2, b2, out);
}